// Round 4
// baseline (155.516 us; speedup 1.0000x reference)
//
#include <hip/hip_runtime.h>
#include <math.h>

typedef float v2f __attribute__((ext_vector_type(2)));
typedef float v4f __attribute__((ext_vector_type(4)));

#define TPB 256
#define PEPASS 256  // pair-entries staged in LDS per pass (8 KB)

// For each query point a in A: partial min over a chunk of B of
// t = c - 2 a.b (c=|b|^2); partial written = a^2 + min(t) = min d^2.
// B chunk is staged in LDS as pair-entries {-2x0,-2x1,-2y0,-2y1},{-2z0,-2z1,c0,c1}.
// dir (blockIdx.z): 0 = forward (A=P, B=T), 1 = backward (A=T, B=P).
template<int KXV>
__global__ __launch_bounds__(TPB, 8) void chamfer_minsq(
    const float* __restrict__ P, int NP,
    const float* __restrict__ T, int NT,
    float* __restrict__ partF, float* __restrict__ partB, int YC)
{
    const int dir = blockIdx.z;
    const float* __restrict__ A = dir ? T : P;
    const float* __restrict__ B = dir ? P : T;
    const int NA = dir ? NT : NP;
    const int NB = dir ? NP : NT;
    float* __restrict__ part = dir ? partB : partF;

    const int tid = threadIdx.x;
    const int xbase = blockIdx.x * (TPB * KXV);
    if (xbase >= NA) return;

    const int NBp = (NB + 1) >> 1;               // pair-entry count
    const int chunkp = (NBp + YC - 1) / YC;
    const int p0 = blockIdx.y * chunkp;
    const int p1 = min(p0 + chunkp, NBp);

    if (p0 >= p1) {                               // empty chunk: neutral partials
#pragma unroll
        for (int k = 0; k < KXV; k++) {
            const int xi = xbase + k * TPB + tid;
            if (xi < NA) part[(size_t)blockIdx.y * NA + xi] = 3.4e38f;
        }
        return;
    }

    v2f axp[KXV], ayp[KXV], azp[KXV];
    float m[KXV], a2[KXV];
#pragma unroll
    for (int k = 0; k < KXV; k++) {
        const int xi = xbase + k * TPB + tid;
        const int xc = xi < NA ? xi : NA - 1;     // duplicate query, harmless
        const float ax = A[3*xc], ay = A[3*xc+1], az = A[3*xc+2];
        axp[k] = (v2f){ax, ax};
        ayp[k] = (v2f){ay, ay};
        azp[k] = (v2f){az, az};
        a2[k] = ax*ax + ay*ay + az*az;
        m[k] = 3.4e38f;
    }

    __shared__ v4f lds[2 * PEPASS];               // 8 KB

    for (int base = p0; base < p1; base += PEPASS) {
        const int npe = min(PEPASS, p1 - base);

        // cooperative stage: raw B -> transformed pair-entries in LDS
        for (int t = tid; t < npe; t += TPB) {
            const int j = base + t;
            const int i0 = 2 * j;
            const int i1 = min(2 * j + 1, NB - 1);    // odd NB: duplicate last
            const float x0 = B[3*i0], y0 = B[3*i0+1], z0 = B[3*i0+2];
            const float x1 = B[3*i1], y1 = B[3*i1+1], z1 = B[3*i1+2];
            lds[2*t]   = (v4f){-2.f*x0, -2.f*x1, -2.f*y0, -2.f*y1};
            lds[2*t+1] = (v4f){-2.f*z0, -2.f*z1,
                               x0*x0 + y0*y0 + z0*z0,
                               x1*x1 + y1*y1 + z1*z1};
        }
        __syncthreads();

#pragma unroll 4
        for (int jj = 0; jj < npe; ++jj) {
            const v4f q0 = lds[2*jj];                 // ds_read_b128 broadcast
            const v4f q1 = lds[2*jj + 1];
            const v2f mx = __builtin_shufflevector(q0, q0, 0, 1);
            const v2f my = __builtin_shufflevector(q0, q0, 2, 3);
            const v2f mz = __builtin_shufflevector(q1, q1, 0, 1);
            const v2f cv = __builtin_shufflevector(q1, q1, 2, 3);
#pragma unroll
            for (int k = 0; k < KXV; k++) {
                v2f t;
                asm("v_pk_fma_f32 %0, %1, %2, %3" : "=v"(t) : "v"(azp[k]), "v"(mz), "v"(cv));
                asm("v_pk_fma_f32 %0, %1, %2, %0" : "+v"(t) : "v"(ayp[k]), "v"(my));
                asm("v_pk_fma_f32 %0, %1, %2, %0" : "+v"(t) : "v"(axp[k]), "v"(mx));
                asm("v_min3_f32 %0, %0, %1, %2"   : "+v"(m[k]) : "v"(t.x), "v"(t.y));
            }
        }
        __syncthreads();
    }

#pragma unroll
    for (int k = 0; k < KXV; k++) {
        const int xi = xbase + k * TPB + tid;
        if (xi < NA) part[(size_t)blockIdx.y * NA + xi] = a2[k] + m[k];
    }
}

// Min-reduce partial d^2 across chunks, sqrt, scale by 1/N, sum into *out.
__global__ __launch_bounds__(TPB) void chamfer_reduce(
    const float* __restrict__ partF, int NP,
    const float* __restrict__ partB, int NT,
    int YC, float scaleF, float scaleB, float* __restrict__ out)
{
    const int gid = blockIdx.x * TPB + threadIdx.x;
    float val = 0.f;
    if (gid < NP) {
        float mn = 3.4e38f;
        for (int c = 0; c < YC; c++) mn = fminf(mn, partF[(size_t)c * NP + gid]);
        val = sqrtf(fmaxf(mn, 0.f)) * scaleF;
    } else if (gid < NP + NT) {
        const int i = gid - NP;
        float mn = 3.4e38f;
        for (int c = 0; c < YC; c++) mn = fminf(mn, partB[(size_t)c * NT + i]);
        val = sqrtf(fmaxf(mn, 0.f)) * scaleB;
    }

#pragma unroll
    for (int off = 32; off > 0; off >>= 1) val += __shfl_down(val, off);
    __shared__ float red[TPB / 64];
    const int lane = threadIdx.x & 63;
    const int w = threadIdx.x >> 6;
    if (lane == 0) red[w] = val;
    __syncthreads();
    if (threadIdx.x == 0) {
        float s = 0.f;
#pragma unroll
        for (int i = 0; i < TPB / 64; i++) s += red[i];
        atomicAdd(out, s);
    }
}

extern "C" void kernel_launch(void* const* d_in, const int* in_sizes, int n_in,
                              void* d_out, int out_size, void* d_ws, size_t ws_size,
                              hipStream_t stream) {
    const float* P = (const float*)d_in[0];
    const float* T = (const float*)d_in[1];
    const int NP = in_sizes[0] / 3;
    const int NT = in_sizes[1] / 3;
    float* out = (float*)d_out;

    int YC = 128;
    while (YC > 1 && (size_t)YC * (size_t)(NP + NT) * sizeof(float) > ws_size)
        YC >>= 1;

    float* partF = (float*)d_ws;
    float* partB = partF + (size_t)YC * NP;

    const int NAmax = NP > NT ? NP : NT;
    // Target >= 2048 blocks (8 blocks/CU): KX=8 when YC=128; otherwise KX=4
    // doubles blockIdx.x so the grid stays large even with fewer y-chunks.
    if (YC >= 128) {
        const int gx = (NAmax + TPB * 8 - 1) / (TPB * 8);
        dim3 grid(gx, YC, 2);
        chamfer_minsq<8><<<grid, TPB, 0, stream>>>(P, NP, T, NT, partF, partB, YC);
    } else {
        const int gx = (NAmax + TPB * 4 - 1) / (TPB * 4);
        dim3 grid(gx, YC, 2);
        chamfer_minsq<4><<<grid, TPB, 0, stream>>>(P, NP, T, NT, partF, partB, YC);
    }

    hipMemsetAsync(d_out, 0, sizeof(float), stream);

    const int rblocks = (NP + NT + TPB - 1) / TPB;
    chamfer_reduce<<<rblocks, TPB, 0, stream>>>(partF, NP, partB, NT, YC,
                                                1.0f / (float)NP, 1.0f / (float)NT, out);
}

// Round 5
// 85.155 us; speedup vs baseline: 1.8263x; 1.8263x over previous
//
#include <hip/hip_runtime.h>
#include <math.h>

typedef float v2f __attribute__((ext_vector_type(2)));
typedef float v4f __attribute__((ext_vector_type(4)));

#define TPB 256
#define PEPASS 256  // pair-entries staged in LDS per pass (8 KB)

// For each query point a in A: partial min over a chunk of B of
// t = c - 2 a.b (c=|b|^2); partial written = a^2 + min(t) = min d^2.
// B chunk is staged in LDS as pair-entries {-2x0,-2x1,-2y0,-2y1},{-2z0,-2z1,c0,c1}.
// dir (blockIdx.z): 0 = forward (A=P, B=T), 1 = backward (A=T, B=P).
// NOTE: launch_bounds min-waves MUST stay at 4: (256,8) caps VGPR at 64 ->
// the compiler squeezed to 32 and spilled KX=8 state to scratch (round 4:
// WRITE_SIZE 8->112 MB, VALUBusy 23%, 2.4x regression). VGPR=60 at (256,4)
// already permits 8 waves/SIMD naturally.
template<int KXV>
__global__ __launch_bounds__(TPB, 4) void chamfer_minsq(
    const float* __restrict__ P, int NP,
    const float* __restrict__ T, int NT,
    float* __restrict__ partF, float* __restrict__ partB, int YC)
{
    const int dir = blockIdx.z;
    const float* __restrict__ A = dir ? T : P;
    const float* __restrict__ B = dir ? P : T;
    const int NA = dir ? NT : NP;
    const int NB = dir ? NP : NT;
    float* __restrict__ part = dir ? partB : partF;

    const int tid = threadIdx.x;
    const int xbase = blockIdx.x * (TPB * KXV);
    if (xbase >= NA) return;

    const int NBp = (NB + 1) >> 1;               // pair-entry count
    const int chunkp = (NBp + YC - 1) / YC;
    const int p0 = blockIdx.y * chunkp;
    const int p1 = min(p0 + chunkp, NBp);

    if (p0 >= p1) {                               // empty chunk: neutral partials
#pragma unroll
        for (int k = 0; k < KXV; k++) {
            const int xi = xbase + k * TPB + tid;
            if (xi < NA) part[(size_t)blockIdx.y * NA + xi] = 3.4e38f;
        }
        return;
    }

    v2f axp[KXV], ayp[KXV], azp[KXV];
    float m[KXV], a2[KXV];
#pragma unroll
    for (int k = 0; k < KXV; k++) {
        const int xi = xbase + k * TPB + tid;
        const int xc = xi < NA ? xi : NA - 1;     // duplicate query, harmless
        const float ax = A[3*xc], ay = A[3*xc+1], az = A[3*xc+2];
        axp[k] = (v2f){ax, ax};
        ayp[k] = (v2f){ay, ay};
        azp[k] = (v2f){az, az};
        a2[k] = ax*ax + ay*ay + az*az;
        m[k] = 3.4e38f;
    }

    __shared__ v4f lds[2 * PEPASS];               // 8 KB

    for (int base = p0; base < p1; base += PEPASS) {
        const int npe = min(PEPASS, p1 - base);

        // cooperative stage: raw B -> transformed pair-entries in LDS
        for (int t = tid; t < npe; t += TPB) {
            const int j = base + t;
            const int i0 = 2 * j;
            const int i1 = min(2 * j + 1, NB - 1);    // odd NB: duplicate last
            const float x0 = B[3*i0], y0 = B[3*i0+1], z0 = B[3*i0+2];
            const float x1 = B[3*i1], y1 = B[3*i1+1], z1 = B[3*i1+2];
            lds[2*t]   = (v4f){-2.f*x0, -2.f*x1, -2.f*y0, -2.f*y1};
            lds[2*t+1] = (v4f){-2.f*z0, -2.f*z1,
                               x0*x0 + y0*y0 + z0*z0,
                               x1*x1 + y1*y1 + z1*z1};
        }
        __syncthreads();

#pragma unroll 4
        for (int jj = 0; jj < npe; ++jj) {
            const v4f q0 = lds[2*jj];                 // ds_read_b128 broadcast
            const v4f q1 = lds[2*jj + 1];
            const v2f mx = __builtin_shufflevector(q0, q0, 0, 1);
            const v2f my = __builtin_shufflevector(q0, q0, 2, 3);
            const v2f mz = __builtin_shufflevector(q1, q1, 0, 1);
            const v2f cv = __builtin_shufflevector(q1, q1, 2, 3);
#pragma unroll
            for (int k = 0; k < KXV; k++) {
                v2f t;
                asm("v_pk_fma_f32 %0, %1, %2, %3" : "=v"(t) : "v"(azp[k]), "v"(mz), "v"(cv));
                asm("v_pk_fma_f32 %0, %1, %2, %0" : "+v"(t) : "v"(ayp[k]), "v"(my));
                asm("v_pk_fma_f32 %0, %1, %2, %0" : "+v"(t) : "v"(axp[k]), "v"(mx));
                asm("v_min3_f32 %0, %0, %1, %2"   : "+v"(m[k]) : "v"(t.x), "v"(t.y));
            }
        }
        __syncthreads();
    }

#pragma unroll
    for (int k = 0; k < KXV; k++) {
        const int xi = xbase + k * TPB + tid;
        if (xi < NA) part[(size_t)blockIdx.y * NA + xi] = a2[k] + m[k];
    }
}

// Min-reduce partial d^2 across chunks, sqrt, scale by 1/N, sum into *out.
__global__ __launch_bounds__(TPB) void chamfer_reduce(
    const float* __restrict__ partF, int NP,
    const float* __restrict__ partB, int NT,
    int YC, float scaleF, float scaleB, float* __restrict__ out)
{
    const int gid = blockIdx.x * TPB + threadIdx.x;
    float val = 0.f;
    if (gid < NP) {
        float mn = 3.4e38f;
        for (int c = 0; c < YC; c++) mn = fminf(mn, partF[(size_t)c * NP + gid]);
        val = sqrtf(fmaxf(mn, 0.f)) * scaleF;
    } else if (gid < NP + NT) {
        const int i = gid - NP;
        float mn = 3.4e38f;
        for (int c = 0; c < YC; c++) mn = fminf(mn, partB[(size_t)c * NT + i]);
        val = sqrtf(fmaxf(mn, 0.f)) * scaleB;
    }

#pragma unroll
    for (int off = 32; off > 0; off >>= 1) val += __shfl_down(val, off);
    __shared__ float red[TPB / 64];
    const int lane = threadIdx.x & 63;
    const int w = threadIdx.x >> 6;
    if (lane == 0) red[w] = val;
    __syncthreads();
    if (threadIdx.x == 0) {
        float s = 0.f;
#pragma unroll
        for (int i = 0; i < TPB / 64; i++) s += red[i];
        atomicAdd(out, s);
    }
}

extern "C" void kernel_launch(void* const* d_in, const int* in_sizes, int n_in,
                              void* d_out, int out_size, void* d_ws, size_t ws_size,
                              hipStream_t stream) {
    const float* P = (const float*)d_in[0];
    const float* T = (const float*)d_in[1];
    const int NP = in_sizes[0] / 3;
    const int NT = in_sizes[1] / 3;
    float* out = (float*)d_out;

    int YC = 128;
    while (YC > 1 && (size_t)YC * (size_t)(NP + NT) * sizeof(float) > ws_size)
        YC >>= 1;

    float* partF = (float*)d_ws;
    float* partB = partF + (size_t)YC * NP;

    const int NAmax = NP > NT ? NP : NT;
    // Target >= 2048 blocks (8 blocks/CU): KX=8 when YC=128; otherwise KX=4
    // doubles blockIdx.x so the grid stays large even with fewer y-chunks.
    if (YC >= 128) {
        const int gx = (NAmax + TPB * 8 - 1) / (TPB * 8);
        dim3 grid(gx, YC, 2);
        chamfer_minsq<8><<<grid, TPB, 0, stream>>>(P, NP, T, NT, partF, partB, YC);
    } else {
        const int gx = (NAmax + TPB * 4 - 1) / (TPB * 4);
        dim3 grid(gx, YC, 2);
        chamfer_minsq<4><<<grid, TPB, 0, stream>>>(P, NP, T, NT, partF, partB, YC);
    }

    hipMemsetAsync(d_out, 0, sizeof(float), stream);

    const int rblocks = (NP + NT + TPB - 1) / TPB;
    chamfer_reduce<<<rblocks, TPB, 0, stream>>>(partF, NP, partB, NT, YC,
                                                1.0f / (float)NP, 1.0f / (float)NT, out);
}

// Round 6
// 58.596 us; speedup vs baseline: 2.6540x; 1.4533x over previous
//
#include <hip/hip_runtime.h>
#include <math.h>

typedef float v2f __attribute__((ext_vector_type(2)));
typedef float v4f __attribute__((ext_vector_type(4)));

#define TPB 256
#define KX 4        // query points per thread
#define PEPASS 128  // pair-entries staged in LDS per pass (4 KB)

// For each query point a in A: min over a chunk of B of t = c - 2 a.b
// (c=|b|^2); then atomicMin(gmin[a], bits(a^2 + min t)) -- nonneg fp32 bit
// patterns are monotone as uint, so uint atomicMin == float min, exactly,
// order-independent. B staged in LDS as {-2x0,-2x1,-2y0,-2y1},{-2z0,-2z1,c0,c1}.
// dir (blockIdx.z): 0 = forward (A=P, B=T), 1 = backward (A=T, B=P).
// NOTE: (256,8) caps VGPR at 64; KX=4 live-set ~54 fits. KX=8 did NOT (round 4
// spilled: WRITE_SIZE 8->112MB). Watch WRITE_SIZE as the spill sentinel.
__global__ __launch_bounds__(TPB, 8) void chamfer_minsq(
    const float* __restrict__ P, int NP,
    const float* __restrict__ T, int NT,
    unsigned* __restrict__ gminF, unsigned* __restrict__ gminB, int YC)
{
    const int dir = blockIdx.z;
    const float* __restrict__ A = dir ? T : P;
    const float* __restrict__ B = dir ? P : T;
    const int NA = dir ? NT : NP;
    const int NB = dir ? NP : NT;
    unsigned* __restrict__ gmin = dir ? gminB : gminF;

    const int tid = threadIdx.x;
    const int xbase = blockIdx.x * (TPB * KX);
    if (xbase >= NA) return;

    const int NBp = (NB + 1) >> 1;               // pair-entry count
    const int chunkp = (NBp + YC - 1) / YC;
    const int p0 = blockIdx.y * chunkp;
    const int p1 = min(p0 + chunkp, NBp);
    if (p0 >= p1) return;                         // empty chunk: chunk 0 covers all queries

    v2f axp[KX], ayp[KX], azp[KX];
    float m[KX], a2[KX];
#pragma unroll
    for (int k = 0; k < KX; k++) {
        const int xi = xbase + k * TPB + tid;
        const int xc = xi < NA ? xi : NA - 1;     // duplicate query, harmless
        const float ax = A[3*xc], ay = A[3*xc+1], az = A[3*xc+2];
        axp[k] = (v2f){ax, ax};
        ayp[k] = (v2f){ay, ay};
        azp[k] = (v2f){az, az};
        a2[k] = ax*ax + ay*ay + az*az;
        m[k] = 3.4e38f;
    }

    __shared__ v4f lds[2 * PEPASS];               // 4 KB

    for (int base = p0; base < p1; base += PEPASS) {
        const int npe = min(PEPASS, p1 - base);

        // cooperative stage: raw B -> transformed pair-entries in LDS
        for (int t = tid; t < npe; t += TPB) {
            const int j = base + t;
            const int i0 = 2 * j;
            const int i1 = min(2 * j + 1, NB - 1);    // odd NB: duplicate last
            const float x0 = B[3*i0], y0 = B[3*i0+1], z0 = B[3*i0+2];
            const float x1 = B[3*i1], y1 = B[3*i1+1], z1 = B[3*i1+2];
            lds[2*t]   = (v4f){-2.f*x0, -2.f*x1, -2.f*y0, -2.f*y1};
            lds[2*t+1] = (v4f){-2.f*z0, -2.f*z1,
                               x0*x0 + y0*y0 + z0*z0,
                               x1*x1 + y1*y1 + z1*z1};
        }
        __syncthreads();

#pragma unroll 4
        for (int jj = 0; jj < npe; ++jj) {
            const v4f q0 = lds[2*jj];                 // ds_read_b128 broadcast
            const v4f q1 = lds[2*jj + 1];
            const v2f mx = (v2f){q0.x, q0.y};
            const v2f my = (v2f){q0.z, q0.w};
            const v2f mz = (v2f){q1.x, q1.y};
            const v2f cv = (v2f){q1.z, q1.w};
#pragma unroll
            for (int k = 0; k < KX; k++) {
                v2f t = azp[k] * mz + cv;             // fp-contract -> (pk_)fma
                t = ayp[k] * my + t;
                t = axp[k] * mx + t;
                m[k] = fminf(m[k], fminf(t.x, t.y));  // -> v_min3_f32
            }
        }
        __syncthreads();
    }

#pragma unroll
    for (int k = 0; k < KX; k++) {
        const int xi = xbase + k * TPB + tid;
        if (xi < NA)
            atomicMin(&gmin[xi], __float_as_uint(a2[k] + m[k]));
    }
}

// gmin bits -> sqrt -> scaled sum into *out.
__global__ __launch_bounds__(TPB) void chamfer_final(
    const unsigned* __restrict__ gminF, int NP,
    const unsigned* __restrict__ gminB, int NT,
    float scaleF, float scaleB, float* __restrict__ out)
{
    const int gid = blockIdx.x * TPB + threadIdx.x;
    float val = 0.f;
    if (gid < NP) {
        val = sqrtf(fmaxf(__uint_as_float(gminF[gid]), 0.f)) * scaleF;
    } else if (gid < NP + NT) {
        val = sqrtf(fmaxf(__uint_as_float(gminB[gid - NP]), 0.f)) * scaleB;
    }

#pragma unroll
    for (int off = 32; off > 0; off >>= 1) val += __shfl_down(val, off);
    __shared__ float red[TPB / 64];
    const int lane = threadIdx.x & 63;
    const int w = threadIdx.x >> 6;
    if (lane == 0) red[w] = val;
    __syncthreads();
    if (threadIdx.x == 0) {
        float s = 0.f;
#pragma unroll
        for (int i = 0; i < TPB / 64; i++) s += red[i];
        atomicAdd(out, s);
    }
}

extern "C" void kernel_launch(void* const* d_in, const int* in_sizes, int n_in,
                              void* d_out, int out_size, void* d_ws, size_t ws_size,
                              hipStream_t stream) {
    const float* P = (const float*)d_in[0];
    const float* T = (const float*)d_in[1];
    const int NP = in_sizes[0] / 3;
    const int NT = in_sizes[1] / 3;
    float* out = (float*)d_out;

    unsigned* gminF = (unsigned*)d_ws;
    unsigned* gminB = gminF + NP;

    // init gmin to 0xFFFFFFFF (uint max) and out to 0, every call (harness
    // poisons once and never re-poisons; we must not rely on leftover state)
    hipMemsetAsync(d_ws, 0xFF, (size_t)(NP + NT) * sizeof(unsigned), stream);
    hipMemsetAsync(d_out, 0, sizeof(float), stream);

    const int YC = 64;   // y-chunks: grid = gx*YC*2 = 2048 blocks (8/CU)
    const int NAmax = NP > NT ? NP : NT;
    const int gx = (NAmax + TPB * KX - 1) / (TPB * KX);
    dim3 grid(gx, YC, 2);
    chamfer_minsq<<<grid, TPB, 0, stream>>>(P, NP, T, NT, gminF, gminB, YC);

    const int fblocks = (NP + NT + TPB - 1) / TPB;
    chamfer_final<<<fblocks, TPB, 0, stream>>>(gminF, NP, gminB, NT,
                                               1.0f / (float)NP, 1.0f / (float)NT, out);
}